// Round 3
// baseline (1968.242 us; speedup 1.0000x reference)
//
#include <hip/hip_runtime.h>
#include <hip/hip_bf16.h>

#define T_SEQ   4096
#define B_BATCH 4
#define E_DIM   1024
#define D_HEAD  128
#define BT      (B_BATCH * T_SEQ)

// ---------------------------------------------------------------------------
// Kernel 1: fused QKV projection + RoPE (fp32)
// grid: (BT/64, 3)  block: 256
// blockIdx.y selects {Q, K, V}. C-tile = 64 rows x 128 cols.
// ---------------------------------------------------------------------------
__global__ __launch_bounds__(256) void qkv_rope_kernel(
    const float* __restrict__ x,     // [BT, E]
    const float* __restrict__ Wq,    // [E, D]
    const float* __restrict__ Wk,
    const float* __restrict__ Wv,
    const float* __restrict__ fcos,  // [T, D/2]
    const float* __restrict__ fsin,
    float* __restrict__ qb,          // [BT, D]
    float* __restrict__ kb,
    float* __restrict__ vb)
{
    const int zi = blockIdx.y;
    const float* __restrict__ W   = (zi == 0) ? Wq : (zi == 1) ? Wk : Wv;
    float*       __restrict__ out = (zi == 0) ? qb : (zi == 1) ? kb : vb;

    const int row0 = blockIdx.x * 64;
    const int tid  = threadIdx.x;
    const int ty   = tid >> 5;   // 0..7
    const int tx   = tid & 31;   // 0..31

    __shared__ float xs[64][36];    // 64 rows x 32 k (pad 36 to break store conflicts)
    __shared__ float ws[32][128];   // 32 k x 128 cols

    float4 acc[8];
    #pragma unroll
    for (int r = 0; r < 8; ++r) acc[r] = make_float4(0.f, 0.f, 0.f, 0.f);

    for (int k0 = 0; k0 < E_DIM; k0 += 32) {
        // stage x tile: 64x32 floats = 512 float4, 256 threads -> 2 each
        #pragma unroll
        for (int it = 0; it < 2; ++it) {
            int i  = tid + it * 256;
            int r  = i >> 3;           // 8 float4 per row
            int c4 = i & 7;
            float4 v = *(const float4*)&x[(size_t)(row0 + r) * E_DIM + k0 + c4 * 4];
            *(float4*)&xs[r][c4 * 4] = v;
        }
        // stage W tile: 32x128 floats = 1024 float4, contiguous in global
        #pragma unroll
        for (int it = 0; it < 4; ++it) {
            int i  = tid + it * 256;
            int r  = i >> 5;           // 32 float4 per row
            int c4 = i & 31;
            *(float4*)&ws[r][c4 * 4] =
                *(const float4*)&W[(size_t)(k0 + r) * D_HEAD + c4 * 4];
        }
        __syncthreads();

        #pragma unroll
        for (int kk = 0; kk < 32; ++kk) {
            float4 wv = *(const float4*)&ws[kk][tx * 4];   // conflict-free b128
            #pragma unroll
            for (int r = 0; r < 8; ++r) {
                float a = xs[ty * 8 + r][kk];              // broadcast across wave
                acc[r].x += a * wv.x;
                acc[r].y += a * wv.y;
                acc[r].z += a * wv.z;
                acc[r].w += a * wv.w;
            }
        }
        __syncthreads();
    }

    // epilogue: RoPE for Q,K (zi<2); plain store for V
    const int h = tx * 2;   // cols tx*4 .. tx*4+3 -> half-dim pairs h, h+1
    #pragma unroll
    for (int r = 0; r < 8; ++r) {
        int row = row0 + ty * 8 + r;
        int t   = row & (T_SEQ - 1);
        float4 v = acc[r];
        if (zi < 2) {
            float c0 = fcos[t * 64 + h],     s0 = fsin[t * 64 + h];
            float c1 = fcos[t * 64 + h + 1], s1 = fsin[t * 64 + h + 1];
            float o0 = v.x * c0 - v.y * s0;
            float o1 = v.x * s0 + v.y * c0;
            float o2 = v.z * c1 - v.w * s1;
            float o3 = v.z * s1 + v.w * c1;
            v = make_float4(o0, o1, o2, o3);
        }
        *(float4*)&out[(size_t)row * D_HEAD + tx * 4] = v;
    }
}

// ---------------------------------------------------------------------------
// Kernel 2: causal flash attention (fp32)
// grid: 512  block: 128
// blockIdx.x -> (qt = x>>2, b = x&3) so sequential blocks balance causal work.
// 32 queries/block; thread = (ql = tid>>2, db = tid&3) owns dims [db*32, db*32+32).
// K/V tiles 32x128 staged in LDS as float4 [c4][slot] with slot = krow ^ (c4>>3)
// (spreads the 4 db-groups across distinct bank quads on every ds_read_b128).
// ---------------------------------------------------------------------------
__global__ __launch_bounds__(128) void attn_kernel(
    const float* __restrict__ q,   // [BT, D] (rope'd)
    const float* __restrict__ k,
    const float* __restrict__ v,
    float* __restrict__ out)       // [BT, D]
{
    const int b     = blockIdx.x & 3;
    const int qt    = blockIdx.x >> 2;
    const int qbase = qt * 32;
    const int tid   = threadIdx.x;
    const int ql    = tid >> 2;    // 0..31 query within tile
    const int db    = tid & 3;     // dim quarter

    const int   qglob = qbase + ql;
    const float scale = 0.08838834764831845f;  // 1/sqrt(128)

    __shared__ float4 Ks4[32][32];  // [c4][slot]
    __shared__ float4 Vs4[32][32];

    // load q row (own 32 dims), fold in softmax scale
    float4 qv[8];
    {
        const float4* qg = (const float4*)&q[(size_t)(b * T_SEQ + qglob) * D_HEAD + db * 32];
        #pragma unroll
        for (int i4 = 0; i4 < 8; ++i4) {
            float4 t = qg[i4];
            qv[i4] = make_float4(t.x * scale, t.y * scale, t.z * scale, t.w * scale);
        }
    }

    float4 o[8];
    #pragma unroll
    for (int i4 = 0; i4 < 8; ++i4) o[i4] = make_float4(0.f, 0.f, 0.f, 0.f);
    float m = -3.0e38f;
    float l = 0.f;

    const int ntiles = qt + 1;
    for (int kt = 0; kt < ntiles; ++kt) {
        const int kbase = kt * 32;
        const bool diag = (kt == qt);
        // stage K/V tile: each 32x128 floats = 1024 float4; 128 thr -> 8 each
        {
            const float4* kg = (const float4*)&k[(size_t)(b * T_SEQ + kbase) * D_HEAD];
            const float4* vg = (const float4*)&v[(size_t)(b * T_SEQ + kbase) * D_HEAD];
            #pragma unroll
            for (int jj = 0; jj < 8; ++jj) {
                int idx  = tid + jj * 128;   // 0..1023
                int krow = idx >> 5;
                int c4   = idx & 31;
                int slot = krow ^ (c4 >> 3);
                Ks4[c4][slot] = kg[idx];
                Vs4[c4][slot] = vg[idx];
            }
        }
        __syncthreads();

        // S = q . k  (partial over own dims, butterfly over the 4-lane group)
        float p[32];
        #pragma unroll
        for (int j = 0; j < 32; ++j) {
            int slot = j ^ db;
            float4 d4 = make_float4(0.f, 0.f, 0.f, 0.f);
            #pragma unroll
            for (int i4 = 0; i4 < 8; ++i4) {
                float4 kv = Ks4[db * 8 + i4][slot];
                d4.x += qv[i4].x * kv.x;
                d4.y += qv[i4].y * kv.y;
                d4.z += qv[i4].z * kv.z;
                d4.w += qv[i4].w * kv.w;
            }
            float s = (d4.x + d4.y) + (d4.z + d4.w);
            s += __shfl_xor(s, 1, 64);
            s += __shfl_xor(s, 2, 64);
            p[j] = s;
        }
        if (diag) {   // causal mask only needed on the diagonal tile
            #pragma unroll
            for (int j = 0; j < 32; ++j)
                if (kbase + j > qglob) p[j] = -3.0e38f;
        }

        // online softmax (identical values across the 4-lane group, bit-exact)
        float mnew = m;
        #pragma unroll
        for (int j = 0; j < 32; ++j) mnew = fmaxf(mnew, p[j]);
        float corr = __expf(m - mnew);
        l *= corr;
        #pragma unroll
        for (int i4 = 0; i4 < 8; ++i4) {
            o[i4].x *= corr; o[i4].y *= corr; o[i4].z *= corr; o[i4].w *= corr;
        }
        float psum = 0.f;
        #pragma unroll
        for (int j = 0; j < 32; ++j) {
            float e = __expf(p[j] - mnew);
            p[j] = e;
            psum += e;
        }
        l += psum;
        m = mnew;

        // O += P . V
        #pragma unroll
        for (int j = 0; j < 32; ++j) {
            float pj   = p[j];
            int   slot = j ^ db;
            #pragma unroll
            for (int i4 = 0; i4 < 8; ++i4) {
                float4 vv = Vs4[db * 8 + i4][slot];
                o[i4].x += pj * vv.x;
                o[i4].y += pj * vv.y;
                o[i4].z += pj * vv.z;
                o[i4].w += pj * vv.w;
            }
        }
        __syncthreads();   // before next tile overwrites LDS
    }

    float inv = 1.f / l;
    float4* og = (float4*)&out[(size_t)(b * T_SEQ + qglob) * D_HEAD + db * 32];
    #pragma unroll
    for (int i4 = 0; i4 < 8; ++i4) {
        og[i4] = make_float4(o[i4].x * inv, o[i4].y * inv, o[i4].z * inv, o[i4].w * inv);
    }
}

// ---------------------------------------------------------------------------
extern "C" void kernel_launch(void* const* d_in, const int* in_sizes, int n_in,
                              void* d_out, int out_size, void* d_ws, size_t ws_size,
                              hipStream_t stream)
{
    (void)in_sizes; (void)n_in; (void)out_size; (void)ws_size;
    const float* x  = (const float*)d_in[0];
    const float* Wq = (const float*)d_in[1];
    const float* Wk = (const float*)d_in[2];
    const float* Wv = (const float*)d_in[3];
    const float* fc = (const float*)d_in[4];
    const float* fs = (const float*)d_in[5];
    float* out = (float*)d_out;

    float* qb = (float*)d_ws;
    float* kb = qb + (size_t)BT * D_HEAD;
    float* vb = kb + (size_t)BT * D_HEAD;

    dim3 g1(BT / 64, 3);
    qkv_rope_kernel<<<g1, 256, 0, stream>>>(x, Wq, Wk, Wv, fc, fs, qb, kb, vb);

    attn_kernel<<<dim3(512), 128, 0, stream>>>(qb, kb, vb, out);
}

// Round 4
// 433.175 us; speedup vs baseline: 4.5438x; 4.5438x over previous
//
#include <hip/hip_runtime.h>
#include <hip/hip_bf16.h>

#define T_SEQ   4096
#define B_BATCH 4
#define E_DIM   1024
#define D_HEAD  128
#define BT      (B_BATCH * T_SEQ)
#define CHUNK   512
#define KVB     32

using bf16x8 = __attribute__((ext_vector_type(8))) short;
using f32x4  = __attribute__((ext_vector_type(4))) float;

static __device__ __forceinline__ unsigned short f2bf(float f) {
    unsigned int b = __float_as_uint(f);
    return (unsigned short)((b + 0x7FFFu + ((b >> 16) & 1u)) >> 16);   // RNE
}
static __device__ __forceinline__ float bf2f(unsigned short u) {
    return __uint_as_float(((unsigned int)u) << 16);
}

// ---------------------------------------------------------------------------
// Kernel 1: fused QKV projection + RoPE (fp32 GEMM core, unchanged from the
// validated round-3 kernel). Epilogue now emits:
//   zi=0: q -> rope -> *1/sqrt(128) -> hi/lo bf16 (qh, ql)
//   zi=1: k -> rope -> hi/lo bf16 (kh, kl)
//   zi=2: v -> bf16 (vb)
// grid: (BT/64, 3)  block: 256
// ---------------------------------------------------------------------------
__global__ __launch_bounds__(256) void qkv_rope_kernel(
    const float* __restrict__ x,     // [BT, E]
    const float* __restrict__ Wq,    // [E, D]
    const float* __restrict__ Wk,
    const float* __restrict__ Wv,
    const float* __restrict__ fcos,  // [T, D/2]
    const float* __restrict__ fsin,
    unsigned short* __restrict__ qh, unsigned short* __restrict__ qlo,
    unsigned short* __restrict__ kh, unsigned short* __restrict__ klo,
    unsigned short* __restrict__ vb)
{
    const int zi = blockIdx.y;
    const float* __restrict__ W = (zi == 0) ? Wq : (zi == 1) ? Wk : Wv;

    const int row0 = blockIdx.x * 64;
    const int tid  = threadIdx.x;
    const int ty   = tid >> 5;   // 0..7
    const int tx   = tid & 31;   // 0..31

    __shared__ float xs[64][36];
    __shared__ float ws[32][128];

    float4 acc[8];
    #pragma unroll
    for (int r = 0; r < 8; ++r) acc[r] = make_float4(0.f, 0.f, 0.f, 0.f);

    for (int k0 = 0; k0 < E_DIM; k0 += 32) {
        #pragma unroll
        for (int it = 0; it < 2; ++it) {
            int i  = tid + it * 256;
            int r  = i >> 3;
            int c4 = i & 7;
            float4 v = *(const float4*)&x[(size_t)(row0 + r) * E_DIM + k0 + c4 * 4];
            *(float4*)&xs[r][c4 * 4] = v;
        }
        #pragma unroll
        for (int it = 0; it < 4; ++it) {
            int i  = tid + it * 256;
            int r  = i >> 5;
            int c4 = i & 31;
            *(float4*)&ws[r][c4 * 4] =
                *(const float4*)&W[(size_t)(k0 + r) * D_HEAD + c4 * 4];
        }
        __syncthreads();

        #pragma unroll
        for (int kk = 0; kk < 32; ++kk) {
            float4 wv = *(const float4*)&ws[kk][tx * 4];
            #pragma unroll
            for (int r = 0; r < 8; ++r) {
                float a = xs[ty * 8 + r][kk];
                acc[r].x += a * wv.x;
                acc[r].y += a * wv.y;
                acc[r].z += a * wv.z;
                acc[r].w += a * wv.w;
            }
        }
        __syncthreads();
    }

    const float SCALE = 0.08838834764831845f;  // 1/sqrt(128)
    const int h = tx * 2;
    #pragma unroll
    for (int r = 0; r < 8; ++r) {
        int row = row0 + ty * 8 + r;
        int t   = row & (T_SEQ - 1);
        float4 v = acc[r];
        if (zi < 2) {
            float c0 = fcos[t * 64 + h],     s0 = fsin[t * 64 + h];
            float c1 = fcos[t * 64 + h + 1], s1 = fsin[t * 64 + h + 1];
            float o0 = v.x * c0 - v.y * s0;
            float o1 = v.x * s0 + v.y * c0;
            float o2 = v.z * c1 - v.w * s1;
            float o3 = v.z * s1 + v.w * c1;
            v = make_float4(o0, o1, o2, o3);
            if (zi == 0) { v.x *= SCALE; v.y *= SCALE; v.z *= SCALE; v.w *= SCALE; }
        }
        size_t ofs = (size_t)row * D_HEAD + tx * 4;
        if (zi == 2) {
            ushort4 sv;
            sv.x = f2bf(v.x); sv.y = f2bf(v.y); sv.z = f2bf(v.z); sv.w = f2bf(v.w);
            *reinterpret_cast<ushort4*>(&vb[ofs]) = sv;
        } else {
            ushort4 hv, lv;
            hv.x = f2bf(v.x); lv.x = f2bf(v.x - bf2f(hv.x));
            hv.y = f2bf(v.y); lv.y = f2bf(v.y - bf2f(hv.y));
            hv.z = f2bf(v.z); lv.z = f2bf(v.z - bf2f(hv.z));
            hv.w = f2bf(v.w); lv.w = f2bf(v.w - bf2f(hv.w));
            unsigned short* oh = (zi == 0) ? qh  : kh;
            unsigned short* ol = (zi == 0) ? qlo : klo;
            *reinterpret_cast<ushort4*>(&oh[ofs]) = hv;
            *reinterpret_cast<ushort4*>(&ol[ofs]) = lv;
        }
    }
}

// ---------------------------------------------------------------------------
// Kernel 2: V transpose  vb[BT,128] -> vt[B][128][T]  (bf16)
// grid: 4*64  block: 256
// ---------------------------------------------------------------------------
__global__ __launch_bounds__(256) void vtrans_kernel(
    const unsigned short* __restrict__ vb,
    unsigned short* __restrict__ vt)
{
    const int t0 = (blockIdx.x & 63) * 64;
    const int b  = blockIdx.x >> 6;
    const int tid = threadIdx.x;
    __shared__ unsigned short S[64][132];

    #pragma unroll
    for (int i = 0; i < 8; ++i) {
        int idx = tid + i * 256;
        int t  = idx >> 5;
        int c4 = idx & 31;
        *reinterpret_cast<ushort4*>(&S[t][c4 * 4]) =
            *reinterpret_cast<const ushort4*>(&vb[(size_t)(b * T_SEQ + t0 + t) * 128 + c4 * 4]);
    }
    __syncthreads();
    #pragma unroll
    for (int i = 0; i < 8; ++i) {
        int idx = tid + i * 256;
        int d = idx >> 4;
        int c = idx & 15;
        ushort4 val;
        val.x = S[c * 4 + 0][d];
        val.y = S[c * 4 + 1][d];
        val.z = S[c * 4 + 2][d];
        val.w = S[c * 4 + 3][d];
        *reinterpret_cast<ushort4*>(&vt[((size_t)(b * 128 + d)) * T_SEQ + t0 + c * 4]) = val;
    }
}

// ---------------------------------------------------------------------------
// Kernel 3: MFMA flash-attention chunk (split-KV).
// grid: 4*64*8 = 2048 (b, qt of 64 q, chunk of 512 keys); block: 128 (2 waves)
// Wave w owns 32 queries (2 subtiles of 16). S^T = mfma(K, Q) so the S^T
// C-fragment is directly the PV A-fragment after an LDS round-trip of P.
// QK hi/lo (bf16x3); PV direct bf16. Unnormalized partials + (m,l) out.
// ---------------------------------------------------------------------------
__global__ __launch_bounds__(128, 2) void attn_chunk_kernel(
    const unsigned short* __restrict__ qh, const unsigned short* __restrict__ qlo,
    const unsigned short* __restrict__ kh, const unsigned short* __restrict__ klo,
    const unsigned short* __restrict__ vt,   // [B][128][T]
    float* __restrict__ opart,               // [2048][64][128]
    float* __restrict__ mlpart)              // [2048][2][64]
{
    const int bid = blockIdx.x;
    const int c   = bid & 7;
    const int qt  = (bid >> 3) & 63;
    const int b   = bid >> 9;
    const int kstart = c * CHUNK;
    const int qend   = qt * 64 + 64;
    if (kstart >= qend) return;
    const int kend   = min(kstart + CHUNK, qend);
    const int ntiles = (kend - kstart) >> 5;

    const int tid  = threadIdx.x;
    const int w    = tid >> 6;
    const int lane = tid & 63;
    const int col  = lane & 15;
    const int g    = lane >> 4;
    const int qbw  = qt * 64 + w * 32;

    __shared__ unsigned short Kh[KVB * 128];
    __shared__ unsigned short Kl[KVB * 128];
    __shared__ unsigned short Vts[128 * 40];       // pad rows to 80B
    __shared__ unsigned short Pl[2][1024];         // per-wave P (32q x 32k)

    // ---- Q fragments (hoisted, hi/lo) ----
    bf16x8 qhf[2][4], qlf[2][4];
    #pragma unroll
    for (int s = 0; s < 2; ++s) {
        size_t qrow = (size_t)(b * T_SEQ + qbw + s * 16 + col);
        #pragma unroll
        for (int dc = 0; dc < 4; ++dc) {
            int off = dc * 32 + g * 8;
            qhf[s][dc] = *reinterpret_cast<const bf16x8*>(&qh [qrow * 128 + off]);
            qlf[s][dc] = *reinterpret_cast<const bf16x8*>(&qlo[qrow * 128 + off]);
        }
    }

    f32x4 oacc[2][8];
    #pragma unroll
    for (int s = 0; s < 2; ++s)
        #pragma unroll
        for (int db = 0; db < 8; ++db)
            oacc[s][db] = (f32x4){0.f, 0.f, 0.f, 0.f};
    float m_s[2] = {-3.0e38f, -3.0e38f};
    float l_s[2] = {0.f, 0.f};

    char* KhB  = reinterpret_cast<char*>(Kh);
    char* KlB  = reinterpret_cast<char*>(Kl);
    char* VtB  = reinterpret_cast<char*>(Vts);
    char* PlB  = reinterpret_cast<char*>(Pl[w]);

    for (int t = 0; t < ntiles; ++t) {
        const int kbase = kstart + t * KVB;

        // ---- stage K hi/lo: 32x128 bf16, XOR-swizzled rows ----
        #pragma unroll
        for (int i = 0; i < 4; ++i) {
            int idx = tid + i * 128;
            int key = idx >> 4, c16 = idx & 15;
            size_t gofs = ((size_t)(b * T_SEQ + kbase + key)) * 128 + c16 * 8;
            int lofs = (key * 256 + c16 * 16) ^ ((key & 7) << 4);
            *reinterpret_cast<uint4*>(KhB + lofs) = *reinterpret_cast<const uint4*>(&kh [gofs]);
            *reinterpret_cast<uint4*>(KlB + lofs) = *reinterpret_cast<const uint4*>(&klo[gofs]);
        }
        // ---- stage V^T: 128 d-rows x 32 keys, 80B row stride ----
        #pragma unroll
        for (int i = 0; i < 4; ++i) {
            int idx = tid + i * 128;
            int d = idx >> 2, c16 = idx & 3;
            size_t gofs = ((size_t)(b * 128 + d)) * T_SEQ + kbase + c16 * 8;
            int lofs = d * 80 + c16 * 16;
            *reinterpret_cast<uint4*>(VtB + lofs) = *reinterpret_cast<const uint4*>(&vt[gofs]);
        }
        __syncthreads();

        // ---- S^T = K . Q^T  (hi*hi + lo*hi + hi*lo) ----
        f32x4 st[2][2];
        st[0][0] = (f32x4){0,0,0,0}; st[0][1] = (f32x4){0,0,0,0};
        st[1][0] = (f32x4){0,0,0,0}; st[1][1] = (f32x4){0,0,0,0};
        #pragma unroll
        for (int kb = 0; kb < 2; ++kb) {
            #pragma unroll
            for (int dc = 0; dc < 4; ++dc) {
                int lofs = ((kb * 16 + col) * 256 + dc * 64 + g * 16) ^ ((col & 7) << 4);
                bf16x8 khf = *reinterpret_cast<const bf16x8*>(KhB + lofs);
                bf16x8 klf = *reinterpret_cast<const bf16x8*>(KlB + lofs);
                #pragma unroll
                for (int s = 0; s < 2; ++s) {
                    st[s][kb] = __builtin_amdgcn_mfma_f32_16x16x32_bf16(khf, qhf[s][dc], st[s][kb], 0, 0, 0);
                    st[s][kb] = __builtin_amdgcn_mfma_f32_16x16x32_bf16(klf, qhf[s][dc], st[s][kb], 0, 0, 0);
                    st[s][kb] = __builtin_amdgcn_mfma_f32_16x16x32_bf16(khf, qlf[s][dc], st[s][kb], 0, 0, 0);
                }
            }
        }

        // ---- causal mask + online softmax (per q-subtile) ----
        #pragma unroll
        for (int s = 0; s < 2; ++s) {
            int qg = qbw + s * 16 + col;
            #pragma unroll
            for (int kb = 0; kb < 2; ++kb) {
                int keyb = kbase + kb * 16 + g * 4;
                #pragma unroll
                for (int r = 0; r < 4; ++r)
                    if (keyb + r > qg) st[s][kb][r] = -3.0e38f;
            }
            float tmax = st[s][0][0];
            #pragma unroll
            for (int kb = 0; kb < 2; ++kb)
                #pragma unroll
                for (int r = 0; r < 4; ++r) tmax = fmaxf(tmax, st[s][kb][r]);
            tmax = fmaxf(tmax, __shfl_xor(tmax, 16, 64));
            tmax = fmaxf(tmax, __shfl_xor(tmax, 32, 64));
            float mnew = fmaxf(m_s[s], tmax);
            float corr = __expf(m_s[s] - mnew);
            m_s[s] = mnew;
            float psum = 0.f;
            #pragma unroll
            for (int kb = 0; kb < 2; ++kb)
                #pragma unroll
                for (int r = 0; r < 4; ++r) {
                    float e = __expf(st[s][kb][r] - mnew);
                    st[s][kb][r] = e;
                    psum += e;
                }
            psum += __shfl_xor(psum, 16, 64);
            psum += __shfl_xor(psum, 32, 64);
            l_s[s] = l_s[s] * corr + psum;

            // rescale O (corr lives at q=col; O rows are q=g*4+r)
            #pragma unroll
            for (int r = 0; r < 4; ++r) {
                float cr = __shfl(corr, (lane & 48) + g * 4 + r, 64);
                #pragma unroll
                for (int db = 0; db < 8; ++db) oacc[s][db][r] *= cr;
            }

            // P -> LDS (bf16), swizzled
            int q = s * 16 + col;
            #pragma unroll
            for (int kb = 0; kb < 2; ++kb) {
                unsigned int pk0 = (unsigned int)f2bf(st[s][kb][0]) | ((unsigned int)f2bf(st[s][kb][1]) << 16);
                unsigned int pk1 = (unsigned int)f2bf(st[s][kb][2]) | ((unsigned int)f2bf(st[s][kb][3]) << 16);
                int base = q * 64 + (kb * 16 + g * 4) * 2;
                int sw = (q & 3) << 4;
                *reinterpret_cast<unsigned int*>(PlB + ((base    ) ^ sw)) = pk0;
                *reinterpret_cast<unsigned int*>(PlB + ((base + 4) ^ sw)) = pk1;
            }
        }

        // ---- O += P . V  (16x16x32, K=32 keys) ----
        #pragma unroll
        for (int db = 0; db < 8; ++db) {
            int d = db * 16 + col;
            bf16x8 vf = *reinterpret_cast<const bf16x8*>(VtB + d * 80 + g * 16);
            #pragma unroll
            for (int s = 0; s < 2; ++s) {
                int lofs = ((s * 16 + col) * 64 + g * 16) ^ ((col & 3) << 4);
                bf16x8 pf = *reinterpret_cast<const bf16x8*>(PlB + lofs);
                oacc[s][db] = __builtin_amdgcn_mfma_f32_16x16x32_bf16(pf, vf, oacc[s][db], 0, 0, 0);
            }
        }
        __syncthreads();
    }

    // ---- store partials ----
    const int pb = (b * 64 + qt) * 8 + c;
    float* op = opart + (size_t)pb * (64 * 128);
    #pragma unroll
    for (int s = 0; s < 2; ++s)
        #pragma unroll
        for (int db = 0; db < 8; ++db)
            #pragma unroll
            for (int r = 0; r < 4; ++r) {
                int qloc = w * 32 + s * 16 + g * 4 + r;
                op[qloc * 128 + db * 16 + col] = oacc[s][db][r];
            }
    if (g == 0) {
        float* ml = mlpart + (size_t)pb * 128;
        #pragma unroll
        for (int s = 0; s < 2; ++s) {
            ml[     w * 32 + s * 16 + col] = m_s[s];
            ml[64 + w * 32 + s * 16 + col] = l_s[s];
        }
    }
}

// ---------------------------------------------------------------------------
// Kernel 4: combine partials  out = sum_c e^{m_c-M} O'_c / (sum_c l_c e^{m_c-M})
// grid: 4*64  block: 256
// ---------------------------------------------------------------------------
__global__ __launch_bounds__(256) void combine_kernel(
    const float* __restrict__ opart, const float* __restrict__ mlpart,
    float* __restrict__ out)
{
    const int qt  = blockIdx.x & 63;
    const int b   = blockIdx.x >> 6;
    const int nch = (qt >> 3) + 1;
    const int tid = threadIdx.x;
    const int q   = tid >> 2;
    const int d0  = (tid & 3) * 32;
    const int pb0 = (b * 64 + qt) * 8;

    float mv[8], wv[8];
    float M = -3.0e38f;
    #pragma unroll
    for (int cc = 0; cc < 8; ++cc)
        if (cc < nch) {
            mv[cc] = mlpart[(size_t)(pb0 + cc) * 128 + q];
            M = fmaxf(M, mv[cc]);
        }
    float L = 0.f;
    #pragma unroll
    for (int cc = 0; cc < 8; ++cc)
        if (cc < nch) {
            float wgt = __expf(mv[cc] - M);
            wv[cc] = wgt;
            L += mlpart[(size_t)(pb0 + cc) * 128 + 64 + q] * wgt;
        }
    float invL = 1.f / L;

    float4 acc[8];
    #pragma unroll
    for (int i = 0; i < 8; ++i) acc[i] = make_float4(0.f, 0.f, 0.f, 0.f);
    #pragma unroll
    for (int cc = 0; cc < 8; ++cc)
        if (cc < nch) {
            const float4* src = reinterpret_cast<const float4*>(
                &opart[((size_t)(pb0 + cc) * 64 + q) * 128 + d0]);
            float wgt = wv[cc] * invL;
            #pragma unroll
            for (int i = 0; i < 8; ++i) {
                float4 v = src[i];
                acc[i].x += wgt * v.x; acc[i].y += wgt * v.y;
                acc[i].z += wgt * v.z; acc[i].w += wgt * v.w;
            }
        }
    float4* dst = reinterpret_cast<float4*>(&out[((size_t)(b * T_SEQ + qt * 64 + q)) * 128 + d0]);
    #pragma unroll
    for (int i = 0; i < 8; ++i) dst[i] = acc[i];
}

// ---------------------------------------------------------------------------
extern "C" void kernel_launch(void* const* d_in, const int* in_sizes, int n_in,
                              void* d_out, int out_size, void* d_ws, size_t ws_size,
                              hipStream_t stream)
{
    (void)in_sizes; (void)n_in; (void)out_size; (void)ws_size;
    const float* x  = (const float*)d_in[0];
    const float* Wq = (const float*)d_in[1];
    const float* Wk = (const float*)d_in[2];
    const float* Wv = (const float*)d_in[3];
    const float* fc = (const float*)d_in[4];
    const float* fs = (const float*)d_in[5];
    float* out = (float*)d_out;

    const size_t NE = (size_t)BT * 128;          // elements per [BT,128] tensor
    unsigned short* qh  = (unsigned short*)d_ws;
    unsigned short* qlo = qh  + NE;
    unsigned short* kh  = qlo + NE;
    unsigned short* klo = kh  + NE;
    unsigned short* vb  = klo + NE;
    unsigned short* vt  = vb  + NE;              // [B][128][T] == NE elements
    float* opart  = (float*)(vt + NE);           // 2048 * 64 * 128 f32
    float* mlpart = opart + (size_t)2048 * 64 * 128;

    qkv_rope_kernel<<<dim3(BT / 64, 3), 256, 0, stream>>>(
        x, Wq, Wk, Wv, fc, fs, qh, qlo, kh, klo, vb);
    vtrans_kernel<<<256, 256, 0, stream>>>(vb, vt);
    attn_chunk_kernel<<<2048, 128, 0, stream>>>(qh, qlo, kh, klo, vt, opart, mlpart);
    combine_kernel<<<256, 256, 0, stream>>>(opart, mlpart, out);
}

// Round 5
// 324.054 us; speedup vs baseline: 6.0738x; 1.3367x over previous
//
#include <hip/hip_runtime.h>
#include <hip/hip_bf16.h>

#define T_SEQ   4096
#define B_BATCH 4
#define E_DIM   1024
#define D_HEAD  128
#define BT      (B_BATCH * T_SEQ)
#define CHUNK   512
#define KVB     32

using bf16x8 = __attribute__((ext_vector_type(8))) short;
using f32x4  = __attribute__((ext_vector_type(4))) float;

static __device__ __forceinline__ unsigned short f2bf(float f) {
    unsigned int b = __float_as_uint(f);
    return (unsigned short)((b + 0x7FFFu + ((b >> 16) & 1u)) >> 16);   // RNE
}
static __device__ __forceinline__ float bf2f(unsigned short u) {
    return __uint_as_float(((unsigned int)u) << 16);
}
// hi = truncated-bf16(x) (exact prefix), lo = bf16(x - hi); hi+lo ~ x to 2^-17
static __device__ __forceinline__ void split2(float f, unsigned short &h, unsigned short &l) {
    unsigned int b = __float_as_uint(f);
    h = (unsigned short)(b >> 16);
    l = f2bf(f - __uint_as_float(b & 0xFFFF0000u));
}
// split 8 floats -> packed hi uint4 + lo uint4 (bf16 pairs)
static __device__ __forceinline__ void split8(const float4 &a, const float4 &b,
                                              uint4 &hi, uint4 &lo) {
    float fa[8] = {a.x, a.y, a.z, a.w, b.x, b.y, b.z, b.w};
    unsigned int h[4], l[4];
    #pragma unroll
    for (int i = 0; i < 4; ++i) {
        unsigned short h0, h1, l0, l1;
        split2(fa[2 * i],     h0, l0);
        split2(fa[2 * i + 1], h1, l1);
        h[i] = (unsigned int)h0 | ((unsigned int)h1 << 16);
        l[i] = (unsigned int)l0 | ((unsigned int)l1 << 16);
    }
    hi = make_uint4(h[0], h[1], h[2], h[3]);
    lo = make_uint4(l[0], l[1], l[2], l[3]);
}

// ---------------------------------------------------------------------------
// Kernel 0: W -> Wt[zi][n=128][k=1024] bf16 hi/lo (transposed for contiguous-K
// B-fragment reads). grid (16,4,3), block 256.
// ---------------------------------------------------------------------------
__global__ __launch_bounds__(256) void prep_w_kernel(
    const float* __restrict__ Wq, const float* __restrict__ Wk,
    const float* __restrict__ Wv,
    unsigned short* __restrict__ wth, unsigned short* __restrict__ wtl)
{
    const int zi = blockIdx.z;
    const float* __restrict__ W = (zi == 0) ? Wq : (zi == 1) ? Wk : Wv;
    const int k0 = blockIdx.x * 64;
    const int n0 = blockIdx.y * 32;
    const int t  = threadIdx.x;
    __shared__ float S[64][36];

    #pragma unroll
    for (int i = 0; i < 2; ++i) {
        int f = t + i * 256;               // 512 float4 jobs
        int r = f >> 3, c4 = f & 7;
        *(float4*)&S[r][c4 * 4] = *(const float4*)&W[(size_t)(k0 + r) * D_HEAD + n0 + c4 * 4];
    }
    __syncthreads();

    int n = t >> 3, kc = t & 7;            // 32 n-rows x 8 k-chunks
    unsigned int h[4], l[4];
    #pragma unroll
    for (int i = 0; i < 4; ++i) {
        unsigned short h0, h1, l0, l1;
        split2(S[kc * 8 + 2 * i][n],     h0, l0);
        split2(S[kc * 8 + 2 * i + 1][n], h1, l1);
        h[i] = (unsigned int)h0 | ((unsigned int)h1 << 16);
        l[i] = (unsigned int)l0 | ((unsigned int)l1 << 16);
    }
    size_t ofs = ((size_t)zi * 128 + n0 + n) * 1024 + k0 + kc * 8;
    *(uint4*)&wth[ofs] = make_uint4(h[0], h[1], h[2], h[3]);
    *(uint4*)&wtl[ofs] = make_uint4(l[0], l[1], l[2], l[3]);
}

// ---------------------------------------------------------------------------
// Kernel 1: QKV projection as bf16 MFMA GEMM (3-pass hi/lo) + fused RoPE.
// grid (BT/64, 3), block 256 (4 waves, 2x2 of 32x64 wave-tiles).
// A = x (hi/lo split on the fly), B = Wt (pre-split). BK=32.
// LDS tiles [rows][32k] with 16B-slot XOR swizzle: slot ^= (row>>1)&3
// -> ds_read_b128 fragment reads are 2-way (free) instead of 8-way.
// ---------------------------------------------------------------------------
__global__ __launch_bounds__(256) void qkv_gemm_kernel(
    const float* __restrict__ x,
    const unsigned short* __restrict__ wth, const unsigned short* __restrict__ wtl,
    const float* __restrict__ fcos, const float* __restrict__ fsin,
    unsigned short* __restrict__ qh, unsigned short* __restrict__ qlo,
    unsigned short* __restrict__ kh, unsigned short* __restrict__ klo,
    unsigned short* __restrict__ vb)
{
    const int zi   = blockIdx.y;
    const int row0 = blockIdx.x * 64;
    const unsigned short* __restrict__ Bhg = wth + (size_t)zi * 128 * 1024;
    const unsigned short* __restrict__ Blg = wtl + (size_t)zi * 128 * 1024;

    __shared__ unsigned short Ah[64 * 32], Al[64 * 32];     // 4 KB each
    __shared__ unsigned short Bh[128 * 32], Bl[128 * 32];   // 8 KB each

    const int tid  = threadIdx.x;
    const int lane = tid & 63;
    const int w    = tid >> 6;
    const int wr   = w >> 1, wc = w & 1;
    const int colq = lane & 15;
    const int g    = lane >> 4;

    f32x4 acc[2][4];
    #pragma unroll
    for (int m = 0; m < 2; ++m)
        #pragma unroll
        for (int n = 0; n < 4; ++n) acc[m][n] = (f32x4){0.f, 0.f, 0.f, 0.f};

    const int ra = tid >> 2, ca = tid & 3;          // A staging job
    const int sa = ca ^ ((ra >> 1) & 3);            // swizzled slot
    char* AhB = (char*)Ah; char* AlB = (char*)Al;
    char* BhB = (char*)Bh; char* BlB = (char*)Bl;

    for (int k0 = 0; k0 < E_DIM; k0 += 32) {
        // ---- stage A: 64x32 fp32 -> hi/lo bf16, swizzled b128 writes ----
        {
            const float* xp = &x[(size_t)(row0 + ra) * E_DIM + k0 + ca * 8];
            float4 a0 = *(const float4*)xp;
            float4 a1 = *(const float4*)(xp + 4);
            uint4 hi, lo;
            split8(a0, a1, hi, lo);
            *(uint4*)(AhB + ra * 64 + sa * 16) = hi;
            *(uint4*)(AlB + ra * 64 + sa * 16) = lo;
        }
        // ---- stage B: 128x32 bf16 hi/lo from Wt, swizzled ----
        #pragma unroll
        for (int i = 0; i < 2; ++i) {
            int j  = tid + i * 256;
            int rb = j >> 2, cb = j & 3;
            int sb = cb ^ ((rb >> 1) & 3);
            size_t gofs = (size_t)rb * 1024 + k0 + cb * 8;
            *(uint4*)(BhB + rb * 64 + sb * 16) = *(const uint4*)&Bhg[gofs];
            *(uint4*)(BlB + rb * 64 + sb * 16) = *(const uint4*)&Blg[gofs];
        }
        __syncthreads();

        // ---- fragments + 3-pass MFMA ----
        bf16x8 afh[2], afl[2], bfh[4], bfl[4];
        #pragma unroll
        for (int m = 0; m < 2; ++m) {
            int rowA = wr * 32 + m * 16 + colq;
            int off  = rowA * 64 + (g ^ ((rowA >> 1) & 3)) * 16;
            afh[m] = *(const bf16x8*)(AhB + off);
            afl[m] = *(const bf16x8*)(AlB + off);
        }
        #pragma unroll
        for (int n = 0; n < 4; ++n) {
            int rowB = wc * 64 + n * 16 + colq;
            int off  = rowB * 64 + (g ^ ((rowB >> 1) & 3)) * 16;
            bfh[n] = *(const bf16x8*)(BhB + off);
            bfl[n] = *(const bf16x8*)(BlB + off);
        }
        #pragma unroll
        for (int m = 0; m < 2; ++m)
            #pragma unroll
            for (int n = 0; n < 4; ++n) {
                acc[m][n] = __builtin_amdgcn_mfma_f32_16x16x32_bf16(afh[m], bfh[n], acc[m][n], 0, 0, 0);
                acc[m][n] = __builtin_amdgcn_mfma_f32_16x16x32_bf16(afl[m], bfh[n], acc[m][n], 0, 0, 0);
                acc[m][n] = __builtin_amdgcn_mfma_f32_16x16x32_bf16(afh[m], bfl[n], acc[m][n], 0, 0, 0);
            }
        __syncthreads();
    }

    // ---- epilogue: RoPE (q,k) via shfl pair-exchange, hi/lo or bf16 store ----
    const float SCALE = 0.08838834764831845f;   // 1/sqrt(128)
    #pragma unroll
    for (int m = 0; m < 2; ++m)
        #pragma unroll
        for (int n = 0; n < 4; ++n) {
            int col = wc * 64 + n * 16 + colq;
            int h   = col >> 1;
            #pragma unroll
            for (int r = 0; r < 4; ++r) {
                int row = row0 + wr * 32 + m * 16 + g * 4 + r;
                int t   = row & (T_SEQ - 1);
                float val = acc[m][n][r];
                size_t ofs = (size_t)row * D_HEAD + col;
                if (zi == 2) {
                    vb[ofs] = f2bf(val);
                } else {
                    float partner = __shfl_xor(val, 1, 64);
                    float c = fcos[t * 64 + h];
                    float s = fsin[t * 64 + h];
                    float o = (col & 1) ? (partner * s + val * c)
                                        : (val * c - partner * s);
                    if (zi == 0) o *= SCALE;
                    unsigned short hv, lv;
                    split2(o, hv, lv);
                    if (zi == 0) { qh[ofs] = hv; qlo[ofs] = lv; }
                    else         { kh[ofs] = hv; klo[ofs] = lv; }
                }
            }
        }
}

// ---------------------------------------------------------------------------
// Kernel 2: V transpose  vb[BT,128] -> vt[B][128][T]  (bf16)
// ---------------------------------------------------------------------------
__global__ __launch_bounds__(256) void vtrans_kernel(
    const unsigned short* __restrict__ vb,
    unsigned short* __restrict__ vt)
{
    const int t0 = (blockIdx.x & 63) * 64;
    const int b  = blockIdx.x >> 6;
    const int tid = threadIdx.x;
    __shared__ unsigned short S[64][132];

    #pragma unroll
    for (int i = 0; i < 8; ++i) {
        int idx = tid + i * 256;
        int t  = idx >> 5;
        int c4 = idx & 31;
        *reinterpret_cast<ushort4*>(&S[t][c4 * 4]) =
            *reinterpret_cast<const ushort4*>(&vb[(size_t)(b * T_SEQ + t0 + t) * 128 + c4 * 4]);
    }
    __syncthreads();
    #pragma unroll
    for (int i = 0; i < 8; ++i) {
        int idx = tid + i * 256;
        int d = idx >> 4;
        int c = idx & 15;
        ushort4 val;
        val.x = S[c * 4 + 0][d];
        val.y = S[c * 4 + 1][d];
        val.z = S[c * 4 + 2][d];
        val.w = S[c * 4 + 3][d];
        *reinterpret_cast<ushort4*>(&vt[((size_t)(b * 128 + d)) * T_SEQ + t0 + c * 4]) = val;
    }
}

// ---------------------------------------------------------------------------
// Kernel 3: MFMA flash-attention chunk (split-KV) — unchanged from round 4.
// ---------------------------------------------------------------------------
__global__ __launch_bounds__(128, 2) void attn_chunk_kernel(
    const unsigned short* __restrict__ qh, const unsigned short* __restrict__ qlo,
    const unsigned short* __restrict__ kh, const unsigned short* __restrict__ klo,
    const unsigned short* __restrict__ vt,   // [B][128][T]
    float* __restrict__ opart,               // [2048][64][128]
    float* __restrict__ mlpart)              // [2048][2][64]
{
    const int bid = blockIdx.x;
    const int c   = bid & 7;
    const int qt  = (bid >> 3) & 63;
    const int b   = bid >> 9;
    const int kstart = c * CHUNK;
    const int qend   = qt * 64 + 64;
    if (kstart >= qend) return;
    const int kend   = min(kstart + CHUNK, qend);
    const int ntiles = (kend - kstart) >> 5;

    const int tid  = threadIdx.x;
    const int w    = tid >> 6;
    const int lane = tid & 63;
    const int col  = lane & 15;
    const int g    = lane >> 4;
    const int qbw  = qt * 64 + w * 32;

    __shared__ unsigned short Kh[KVB * 128];
    __shared__ unsigned short Kl[KVB * 128];
    __shared__ unsigned short Vts[128 * 40];       // pad rows to 80B
    __shared__ unsigned short Pl[2][1024];         // per-wave P (32q x 32k)

    bf16x8 qhf[2][4], qlf[2][4];
    #pragma unroll
    for (int s = 0; s < 2; ++s) {
        size_t qrow = (size_t)(b * T_SEQ + qbw + s * 16 + col);
        #pragma unroll
        for (int dc = 0; dc < 4; ++dc) {
            int off = dc * 32 + g * 8;
            qhf[s][dc] = *reinterpret_cast<const bf16x8*>(&qh [qrow * 128 + off]);
            qlf[s][dc] = *reinterpret_cast<const bf16x8*>(&qlo[qrow * 128 + off]);
        }
    }

    f32x4 oacc[2][8];
    #pragma unroll
    for (int s = 0; s < 2; ++s)
        #pragma unroll
        for (int db = 0; db < 8; ++db)
            oacc[s][db] = (f32x4){0.f, 0.f, 0.f, 0.f};
    float m_s[2] = {-3.0e38f, -3.0e38f};
    float l_s[2] = {0.f, 0.f};

    char* KhB  = reinterpret_cast<char*>(Kh);
    char* KlB  = reinterpret_cast<char*>(Kl);
    char* VtB  = reinterpret_cast<char*>(Vts);
    char* PlB  = reinterpret_cast<char*>(Pl[w]);

    for (int t = 0; t < ntiles; ++t) {
        const int kbase = kstart + t * KVB;

        #pragma unroll
        for (int i = 0; i < 4; ++i) {
            int idx = tid + i * 128;
            int key = idx >> 4, c16 = idx & 15;
            size_t gofs = ((size_t)(b * T_SEQ + kbase + key)) * 128 + c16 * 8;
            int lofs = (key * 256 + c16 * 16) ^ ((key & 7) << 4);
            *reinterpret_cast<uint4*>(KhB + lofs) = *reinterpret_cast<const uint4*>(&kh [gofs]);
            *reinterpret_cast<uint4*>(KlB + lofs) = *reinterpret_cast<const uint4*>(&klo[gofs]);
        }
        #pragma unroll
        for (int i = 0; i < 4; ++i) {
            int idx = tid + i * 128;
            int d = idx >> 2, c16 = idx & 3;
            size_t gofs = ((size_t)(b * 128 + d)) * T_SEQ + kbase + c16 * 8;
            int lofs = d * 80 + c16 * 16;
            *reinterpret_cast<uint4*>(VtB + lofs) = *reinterpret_cast<const uint4*>(&vt[gofs]);
        }
        __syncthreads();

        f32x4 st[2][2];
        st[0][0] = (f32x4){0,0,0,0}; st[0][1] = (f32x4){0,0,0,0};
        st[1][0] = (f32x4){0,0,0,0}; st[1][1] = (f32x4){0,0,0,0};
        #pragma unroll
        for (int kb = 0; kb < 2; ++kb) {
            #pragma unroll
            for (int dc = 0; dc < 4; ++dc) {
                int lofs = ((kb * 16 + col) * 256 + dc * 64 + g * 16) ^ ((col & 7) << 4);
                bf16x8 khf = *reinterpret_cast<const bf16x8*>(KhB + lofs);
                bf16x8 klf = *reinterpret_cast<const bf16x8*>(KlB + lofs);
                #pragma unroll
                for (int s = 0; s < 2; ++s) {
                    st[s][kb] = __builtin_amdgcn_mfma_f32_16x16x32_bf16(khf, qhf[s][dc], st[s][kb], 0, 0, 0);
                    st[s][kb] = __builtin_amdgcn_mfma_f32_16x16x32_bf16(klf, qhf[s][dc], st[s][kb], 0, 0, 0);
                    st[s][kb] = __builtin_amdgcn_mfma_f32_16x16x32_bf16(khf, qlf[s][dc], st[s][kb], 0, 0, 0);
                }
            }
        }

        #pragma unroll
        for (int s = 0; s < 2; ++s) {
            int qg = qbw + s * 16 + col;
            #pragma unroll
            for (int kb = 0; kb < 2; ++kb) {
                int keyb = kbase + kb * 16 + g * 4;
                #pragma unroll
                for (int r = 0; r < 4; ++r)
                    if (keyb + r > qg) st[s][kb][r] = -3.0e38f;
            }
            float tmax = st[s][0][0];
            #pragma unroll
            for (int kb = 0; kb < 2; ++kb)
                #pragma unroll
                for (int r = 0; r < 4; ++r) tmax = fmaxf(tmax, st[s][kb][r]);
            tmax = fmaxf(tmax, __shfl_xor(tmax, 16, 64));
            tmax = fmaxf(tmax, __shfl_xor(tmax, 32, 64));
            float mnew = fmaxf(m_s[s], tmax);
            float corr = __expf(m_s[s] - mnew);
            m_s[s] = mnew;
            float psum = 0.f;
            #pragma unroll
            for (int kb = 0; kb < 2; ++kb)
                #pragma unroll
                for (int r = 0; r < 4; ++r) {
                    float e = __expf(st[s][kb][r] - mnew);
                    st[s][kb][r] = e;
                    psum += e;
                }
            psum += __shfl_xor(psum, 16, 64);
            psum += __shfl_xor(psum, 32, 64);
            l_s[s] = l_s[s] * corr + psum;

            #pragma unroll
            for (int r = 0; r < 4; ++r) {
                float cr = __shfl(corr, (lane & 48) + g * 4 + r, 64);
                #pragma unroll
                for (int db = 0; db < 8; ++db) oacc[s][db][r] *= cr;
            }

            int q = s * 16 + col;
            #pragma unroll
            for (int kb = 0; kb < 2; ++kb) {
                unsigned int pk0 = (unsigned int)f2bf(st[s][kb][0]) | ((unsigned int)f2bf(st[s][kb][1]) << 16);
                unsigned int pk1 = (unsigned int)f2bf(st[s][kb][2]) | ((unsigned int)f2bf(st[s][kb][3]) << 16);
                int base = q * 64 + (kb * 16 + g * 4) * 2;
                int sw = (q & 3) << 4;
                *reinterpret_cast<unsigned int*>(PlB + ((base    ) ^ sw)) = pk0;
                *reinterpret_cast<unsigned int*>(PlB + ((base + 4) ^ sw)) = pk1;
            }
        }

        #pragma unroll
        for (int db = 0; db < 8; ++db) {
            int d = db * 16 + col;
            bf16x8 vf = *reinterpret_cast<const bf16x8*>(VtB + d * 80 + g * 16);
            #pragma unroll
            for (int s = 0; s < 2; ++s) {
                int lofs = ((s * 16 + col) * 64 + g * 16) ^ ((col & 3) << 4);
                bf16x8 pf = *reinterpret_cast<const bf16x8*>(PlB + lofs);
                oacc[s][db] = __builtin_amdgcn_mfma_f32_16x16x32_bf16(pf, vf, oacc[s][db], 0, 0, 0);
            }
        }
        __syncthreads();
    }

    const int pb = (b * 64 + qt) * 8 + c;
    float* op = opart + (size_t)pb * (64 * 128);
    #pragma unroll
    for (int s = 0; s < 2; ++s)
        #pragma unroll
        for (int db = 0; db < 8; ++db)
            #pragma unroll
            for (int r = 0; r < 4; ++r) {
                int qloc = w * 32 + s * 16 + g * 4 + r;
                op[qloc * 128 + db * 16 + col] = oacc[s][db][r];
            }
    if (g == 0) {
        float* ml = mlpart + (size_t)pb * 128;
        #pragma unroll
        for (int s = 0; s < 2; ++s) {
            ml[     w * 32 + s * 16 + col] = m_s[s];
            ml[64 + w * 32 + s * 16 + col] = l_s[s];
        }
    }
}

// ---------------------------------------------------------------------------
// Kernel 4: combine partials — unchanged from round 4.
// ---------------------------------------------------------------------------
__global__ __launch_bounds__(256) void combine_kernel(
    const float* __restrict__ opart, const float* __restrict__ mlpart,
    float* __restrict__ out)
{
    const int qt  = blockIdx.x & 63;
    const int b   = blockIdx.x >> 6;
    const int nch = (qt >> 3) + 1;
    const int tid = threadIdx.x;
    const int q   = tid >> 2;
    const int d0  = (tid & 3) * 32;
    const int pb0 = (b * 64 + qt) * 8;

    float mv[8], wv[8];
    float M = -3.0e38f;
    #pragma unroll
    for (int cc = 0; cc < 8; ++cc)
        if (cc < nch) {
            mv[cc] = mlpart[(size_t)(pb0 + cc) * 128 + q];
            M = fmaxf(M, mv[cc]);
        }
    float L = 0.f;
    #pragma unroll
    for (int cc = 0; cc < 8; ++cc)
        if (cc < nch) {
            float wgt = __expf(mv[cc] - M);
            wv[cc] = wgt;
            L += mlpart[(size_t)(pb0 + cc) * 128 + 64 + q] * wgt;
        }
    float invL = 1.f / L;

    float4 acc[8];
    #pragma unroll
    for (int i = 0; i < 8; ++i) acc[i] = make_float4(0.f, 0.f, 0.f, 0.f);
    #pragma unroll
    for (int cc = 0; cc < 8; ++cc)
        if (cc < nch) {
            const float4* src = reinterpret_cast<const float4*>(
                &opart[((size_t)(pb0 + cc) * 64 + q) * 128 + d0]);
            float wgt = wv[cc] * invL;
            #pragma unroll
            for (int i = 0; i < 8; ++i) {
                float4 v = src[i];
                acc[i].x += wgt * v.x; acc[i].y += wgt * v.y;
                acc[i].z += wgt * v.z; acc[i].w += wgt * v.w;
            }
        }
    float4* dst = reinterpret_cast<float4*>(&out[((size_t)(b * T_SEQ + qt * 64 + q)) * 128 + d0]);
    #pragma unroll
    for (int i = 0; i < 8; ++i) dst[i] = acc[i];
}

// ---------------------------------------------------------------------------
extern "C" void kernel_launch(void* const* d_in, const int* in_sizes, int n_in,
                              void* d_out, int out_size, void* d_ws, size_t ws_size,
                              hipStream_t stream)
{
    (void)in_sizes; (void)n_in; (void)out_size; (void)ws_size;
    const float* x  = (const float*)d_in[0];
    const float* Wq = (const float*)d_in[1];
    const float* Wk = (const float*)d_in[2];
    const float* Wv = (const float*)d_in[3];
    const float* fc = (const float*)d_in[4];
    const float* fs = (const float*)d_in[5];
    float* out = (float*)d_out;

    const size_t NW = (size_t)3 * 128 * 1024;    // Wt elements
    const size_t NE = (size_t)BT * 128;
    unsigned short* wth = (unsigned short*)d_ws;
    unsigned short* wtl = wth + NW;
    unsigned short* qh  = wtl + NW;
    unsigned short* qlo = qh  + NE;
    unsigned short* kh  = qlo + NE;
    unsigned short* klo = kh  + NE;
    unsigned short* vb  = klo + NE;
    unsigned short* vt  = vb  + NE;
    float* opart  = (float*)(vt + NE);
    float* mlpart = opart + (size_t)2048 * 64 * 128;

    prep_w_kernel<<<dim3(16, 4, 3), 256, 0, stream>>>(Wq, Wk, Wv, wth, wtl);
    qkv_gemm_kernel<<<dim3(BT / 64, 3), 256, 0, stream>>>(
        x, wth, wtl, fc, fs, qh, qlo, kh, klo, vb);
    vtrans_kernel<<<256, 256, 0, stream>>>(vb, vt);
    attn_chunk_kernel<<<2048, 128, 0, stream>>>(qh, qlo, kh, klo, vt, opart, mlpart);
    combine_kernel<<<256, 256, 0, stream>>>(opart, mlpart, out);
}